// Round 1
// 304.757 us; speedup vs baseline: 1.0087x; 1.0087x over previous
//
#include <hip/hip_runtime.h>

// MultiHeadTEAttention MFMA version.
// M=8, NQ=NKV=1024, DX=512, H=8, HD=64, KHID=16, DT=2. f32 in/out, bf16 compute.
// R1: hoist all f32->bf16 conversion + weight transpose into a one-time prep
//     pass; GEMM K-loop is now pure vector-copy staging + MFMA.

typedef unsigned short u16;
typedef unsigned int   u32;
typedef short bf8 __attribute__((ext_vector_type(8)));   // 8 bf16 = 4 VGPR
typedef float f4  __attribute__((ext_vector_type(4)));

#define Mb 8
#define SCALE 0.125f
#define NTOK 4194304   // Mb*1024*512

__device__ __forceinline__ u16 f2bf(float f) {
    union { float f; u32 u; } v; v.f = f;
    u32 r = v.u + 0x7fffu + ((v.u >> 16) & 1u);   // RNE
    return (u16)(r >> 16);
}
__device__ __forceinline__ u32 pk2(float a, float b) {
    return (u32)f2bf(a) | ((u32)f2bf(b) << 16);
}

// ===========================================================================
// prep: one-time conversions.
//   blocks [0,1536):  xq|xk|xv f32 -> bf16 (3*NTOK elems, 8 per thread-iter)
//   blocks [1536,1792): w_q|w_k|w_v|w_out 512x512 f32 -> bf16 TRANSPOSED
//                       dstW[mat][n][k] = w[mat][k][n]
// ===========================================================================
struct PArgs {
    const float* xs[3];
    const float* ws[4];
    u16* dstA;
    u16* dstW;
};

__global__ __launch_bounds__(256) void prep(PArgs p) {
    __shared__ u16 tl[64][80];   // [n within tile][k within tile], padded
    const int tid = threadIdx.x;
    const int b = blockIdx.x;
    if (b < 1536) {
        #pragma unroll
        for (int it = 0; it < 4; ++it) {
            const u32 u = (u32)b * 256u + (u32)tid + (u32)it * 393216u;  // 8-elem unit
            const int arr = u >> 19;                    // NTOK/8 = 524288 units/array
            const size_t off = (size_t)(u & 524287u) * 8;
            const float* s = p.xs[arr];
            float4 a0 = *(const float4*)(s + off);
            float4 a1 = *(const float4*)(s + off + 4);
            uint4 v;
            v.x = pk2(a0.x, a0.y); v.y = pk2(a0.z, a0.w);
            v.z = pk2(a1.x, a1.y); v.w = pk2(a1.z, a1.w);
            *(uint4*)(p.dstA + (size_t)arr * NTOK + off) = v;
        }
    } else {
        const int bb = b - 1536;
        const int mat = bb >> 6, t = bb & 63;
        const int kt = t >> 3, nt = t & 7;              // 64x64 tile coords
        const float* src = p.ws[mat] + (size_t)kt * 64 * 512 + (size_t)nt * 64;
        const int r0 = tid >> 4, c4 = (tid & 15) * 4;
        #pragma unroll
        for (int rr = 0; rr < 4; ++rr) {
            const int row = r0 + rr * 16;               // k within tile
            float4 a = *(const float4*)(src + (size_t)row * 512 + c4);
            tl[c4 + 0][row] = f2bf(a.x);
            tl[c4 + 1][row] = f2bf(a.y);
            tl[c4 + 2][row] = f2bf(a.z);
            tl[c4 + 3][row] = f2bf(a.w);
        }
        __syncthreads();
        u16* dst = p.dstW + (size_t)mat * 262144 + (size_t)nt * 64 * 512 + (size_t)kt * 64;
        #pragma unroll
        for (int i = 0; i < 2; ++i) {
            const int s2 = tid + i * 256;
            const int nrow = s2 >> 3, k8 = (s2 & 7) * 8;
            *(uint4*)(dst + (size_t)nrow * 512 + k8) = *(const uint4*)&tl[nrow][k8];
        }
    }
}

// ===========================================================================
// GEMM: C = A[8192x512] @ W[512x512] (+bias). bf16 MFMA, f32 accumulate.
// A is bf16 row-major; W is bf16 PRE-TRANSPOSED [n][k].
// LDS layout [seg(4)][row(128)][8 bf16]; seg = k-octet of BK=32.
// trans=0: D rows = W-cols (n)  -> store C[tok][n] (packed along n)
// trans=1: D rows = tokens      -> store Vt[mb][n][tokb] (packed along tok)
// ===========================================================================
struct GArgs {
    const u16*   A[3];
    const u16*   W[3];      // transposed [n][512] bf16
    void*        C[3];
    const float* bias;
    int          modeT[3];
    int          outf32;
};

__global__ __launch_bounds__(256) void gemm_mfma(GArgs g) {
    __shared__ u16 Xs[4][128][8];
    __shared__ u16 Ws[4][128][8];

    const int z   = blockIdx.z;
    const int tid = threadIdx.x;
    const int w = tid >> 6, lane = tid & 63, quad = lane >> 4, l16 = lane & 15;
    const int wm = w >> 1, wn = w & 1;
    const int n0 = blockIdx.x * 128, t0 = blockIdx.y * 128;
    const int trans = g.modeT[z];

    f4 acc[4][4];
    #pragma unroll
    for (int i = 0; i < 4; ++i)
        #pragma unroll
        for (int j = 0; j < 4; ++j) acc[i][j] = (f4)0.f;

    const u16* Ap = g.A[z];
    const u16* Wp = g.W[z];

    for (int kc = 0; kc < 512; kc += 32) {
        __syncthreads();
        // ---- stage A tile (128 tok x 32 k): pure uint4 copies ----
        {
            const int row = tid >> 1, half = tid & 1;
            const u16* ap = Ap + (size_t)(t0 + row) * 512 + kc + half * 16;
            uint4 v0 = *(const uint4*)ap;
            uint4 v1 = *(const uint4*)(ap + 8);
            *(uint4*)&Xs[half * 2][row][0]     = v0;
            *(uint4*)&Xs[half * 2 + 1][row][0] = v1;
        }
        // ---- stage W tile: Ws[seg][n][0..7] = Wt[n0+n][kc+seg*8 ..] ----
        #pragma unroll
        for (int i = 0; i < 2; ++i) {
            const int s = tid + i * 256;
            const int seg = s & 3, n = s >> 2;
            *(uint4*)&Ws[seg][n][0] =
                *(const uint4*)(Wp + (size_t)(n0 + n) * 512 + kc + seg * 8);
        }
        __syncthreads();

        // ---- MFMA: aop rows from (trans ? Xs : Ws), bop rows from the other
        const u16 (*Aop)[128][8] = trans ? Xs : Ws;
        const u16 (*Bop)[128][8] = trans ? Ws : Xs;
        const int arow = (trans ? wm : wn) * 64;
        const int brow = (trans ? wn : wm) * 64;
        bf8 af[4], bf[4];
        #pragma unroll
        for (int i = 0; i < 4; ++i) af[i] = *(const bf8*)&Aop[quad][arow + i * 16 + l16][0];
        #pragma unroll
        for (int j = 0; j < 4; ++j) bf[j] = *(const bf8*)&Bop[quad][brow + j * 16 + l16][0];
        #pragma unroll
        for (int i = 0; i < 4; ++i)
            #pragma unroll
            for (int j = 0; j < 4; ++j)
                acc[i][j] = __builtin_amdgcn_mfma_f32_16x16x32_bf16(af[i], bf[j], acc[i][j], 0, 0, 0);
    }

    // ---- epilogue ----
    if (g.outf32) {
        // D[n][tok] f32 + bias -> C[tok][n]
        float* Co = (float*)g.C[z];
        #pragma unroll
        for (int i = 0; i < 4; ++i) {
            const int nb = n0 + wn * 64 + i * 16 + quad * 4;
            float4 bv = *(const float4*)&g.bias[nb];
            #pragma unroll
            for (int j = 0; j < 4; ++j) {
                const int tok = t0 + wm * 64 + j * 16 + l16;
                float4 st;
                st.x = acc[i][j][0] + bv.x; st.y = acc[i][j][1] + bv.y;
                st.z = acc[i][j][2] + bv.z; st.w = acc[i][j][3] + bv.w;
                *(float4*)&Co[(size_t)tok * 512 + nb] = st;
            }
        }
    } else if (!trans) {
        // D[n][tok] -> bf16 C[tok][n]
        u16* C = (u16*)g.C[z];
        #pragma unroll
        for (int i = 0; i < 4; ++i) {
            const int nb = n0 + wn * 64 + i * 16 + quad * 4;
            #pragma unroll
            for (int j = 0; j < 4; ++j) {
                const int tok = t0 + wm * 64 + j * 16 + l16;
                uint2 pw;
                pw.x = pk2(acc[i][j][0], acc[i][j][1]);
                pw.y = pk2(acc[i][j][2], acc[i][j][3]);
                *(uint2*)&C[(size_t)tok * 512 + nb] = pw;
            }
        }
    } else {
        // D[tok][n] -> bf16 Vt[mb][n][tokb]
        u16* Vt = (u16*)g.C[z];
        #pragma unroll
        for (int i = 0; i < 4; ++i) {
            const int tokb = t0 + wm * 64 + i * 16 + quad * 4;
            const int mb = tokb >> 10, tb = tokb & 1023;
            #pragma unroll
            for (int j = 0; j < 4; ++j) {
                const int n = n0 + wn * 64 + j * 16 + l16;
                uint2 pw;
                pw.x = pk2(acc[i][j][0], acc[i][j][1]);
                pw.y = pk2(acc[i][j][2], acc[i][j][3]);
                *(uint2*)&Vt[(size_t)mb * 524288 + (size_t)n * 1024 + tb] = pw;
            }
        }
    }
}

// ===========================================================================
// Fused flash attention (MFMA). Block = (qt, h, m): 64 queries, one head.
// Computes S^T = K·Q^T (D rows = keys, cols = q), online softmax per q-col,
// O^T = Vt·P^T. P round-trips through wave-private LDS.
// ===========================================================================
__global__ __launch_bounds__(256) void attn_mfma(
    const u16* __restrict__ Q, const u16* __restrict__ K,
    const u16* __restrict__ Vt,
    const float* __restrict__ tqp, const float* __restrict__ tkp,
    const float* __restrict__ kw1, const float* __restrict__ kb1,
    const float* __restrict__ kw2,
    u16* __restrict__ O)
{
    __shared__ u16   sK[8][64][8];    // [d-octet][key][8 bf16]
    __shared__ u16   sV[8][64][8];    // [key-octet][d][8 bf16]
    __shared__ float sv[16][68];      // [c][key] : tk @ kw1
    __shared__ u16   sP[4][16][68];   // per-wave P [q][key], +4 pad

    const int tid = threadIdx.x;
    const int w = tid >> 6, lane = tid & 63, quad = lane >> 4, l16 = lane & 15;
    const int qt = blockIdx.x, h = blockIdx.y, m = blockIdx.z;
    const int q0 = qt * 64;
    const size_t qtok = (size_t)m * 1024 + q0 + w * 16 + l16;

    // Q fragments (d = kc*32 + quad*8 + j), q = l16
    bf8 qf[2];
    {
        const u16* qp = Q + qtok * 512 + h * 64 + quad * 8;
        qf[0] = *(const bf8*)qp;
        qf[1] = *(const bf8*)(qp + 32);
    }
    // u_q[c] = tq@kw1 + kb1 ; w2h[c] = kw2[c][h]  (kb2 softmax-invariant)
    float u[16], w2h[16];
    {
        const float t0v = tqp[qtok * 2], t1v = tqp[qtok * 2 + 1];
        #pragma unroll
        for (int c = 0; c < 16; ++c) {
            u[c] = fmaf(t0v, kw1[c], fmaf(t1v, kw1[16 + c], kb1[c]));
            w2h[c] = kw2[c * 8 + h];
        }
    }

    float mrun = -1e30f, lrun = 0.f;
    f4 o[4];
    #pragma unroll
    for (int d = 0; d < 4; ++d) o[d] = (f4)0.f;

    for (int kt = 0; kt < 16; ++kt) {
        const int k0 = kt * 64;
        __syncthreads();
        // ---- stage K tile: sK[seg][key] = K[k0+key][h*64 + seg*8 ..] ----
        #pragma unroll
        for (int i = 0; i < 2; ++i) {
            const int s = tid + i * 256;
            const int seg = s >> 6, key = s & 63;
            const u16* kp = K + ((size_t)m * 1024 + k0 + key) * 512 + h * 64 + seg * 8;
            *(uint4*)&sK[seg][key][0] = *(const uint4*)kp;
        }
        // ---- stage V tile: sV[ks][d] = Vt[h*64+d][k0 + ks*8 ..] ----
        #pragma unroll
        for (int i = 0; i < 2; ++i) {
            const int s = tid + i * 256;
            const int ks = s >> 6, d = s & 63;
            const u16* vp = Vt + (size_t)m * 524288 + (size_t)(h * 64 + d) * 1024 + k0 + ks * 8;
            *(uint4*)&sV[ks][d][0] = *(const uint4*)vp;
        }
        // ---- stage sv[c][k] = tk[k]@kw1[:,c] ----
        {
            const int c = tid >> 4, k4 = (tid & 15) * 4;
            const float* tkq = tkp + ((size_t)m * 1024 + k0 + k4) * 2;
            float4 ta = *(const float4*)tkq;
            float4 tb = *(const float4*)(tkq + 4);
            const float w0 = kw1[c], w1 = kw1[16 + c];
            float4 vv;
            vv.x = fmaf(ta.x, w0, ta.y * w1);
            vv.y = fmaf(ta.z, w0, ta.w * w1);
            vv.z = fmaf(tb.x, w0, tb.y * w1);
            vv.w = fmaf(tb.z, w0, tb.w * w1);
            *(float4*)&sv[c][k4] = vv;
        }
        __syncthreads();

        // ---- S^T = K·Q^T : s[msub] rows = keys msub*16+quad*4+r, col q=l16 ----
        f4 s[4];
        #pragma unroll
        for (int msub = 0; msub < 4; ++msub) {
            bf8 kf0 = *(const bf8*)&sK[quad][msub * 16 + l16][0];
            bf8 kf1 = *(const bf8*)&sK[4 + quad][msub * 16 + l16][0];
            s[msub] = __builtin_amdgcn_mfma_f32_16x16x32_bf16(kf0, qf[0], (f4)0.f, 0, 0, 0);
            s[msub] = __builtin_amdgcn_mfma_f32_16x16x32_bf16(kf1, qf[1], s[msub], 0, 0, 0);
        }
        // ---- bias: s = s*SCALE + sum_c relu(u[c]-v[c,k])*w2h[c] ----
        #pragma unroll
        for (int msub = 0; msub < 4; ++msub) {
            const int kb = msub * 16 + quad * 4;
            f4 b = (f4)0.f;
            #pragma unroll
            for (int c = 0; c < 16; ++c) {
                float4 vv = *(const float4*)&sv[c][kb];
                const float uc = u[c], wc = w2h[c];
                b[0] = fmaf(fmaxf(uc - vv.x, 0.f), wc, b[0]);
                b[1] = fmaf(fmaxf(uc - vv.y, 0.f), wc, b[1]);
                b[2] = fmaf(fmaxf(uc - vv.z, 0.f), wc, b[2]);
                b[3] = fmaf(fmaxf(uc - vv.w, 0.f), wc, b[3]);
            }
            s[msub] = s[msub] * SCALE + b;
        }
        // ---- online softmax over keys (rows spread over quads) ----
        float mx = -1e30f;
        #pragma unroll
        for (int msub = 0; msub < 4; ++msub) {
            mx = fmaxf(mx, fmaxf(fmaxf(s[msub][0], s[msub][1]),
                                 fmaxf(s[msub][2], s[msub][3])));
        }
        mx = fmaxf(mx, __shfl_xor(mx, 16));
        mx = fmaxf(mx, __shfl_xor(mx, 32));
        const float mnew = fmaxf(mrun, mx);
        const float alpha = __expf(mrun - mnew);
        float ps = 0.f;
        #pragma unroll
        for (int msub = 0; msub < 4; ++msub) {
            #pragma unroll
            for (int r = 0; r < 4; ++r) {
                float p = __expf(s[msub][r] - mnew);
                s[msub][r] = p;
                ps += p;
            }
        }
        ps += __shfl_xor(ps, 16);
        ps += __shfl_xor(ps, 32);
        lrun = lrun * alpha + ps;
        mrun = mnew;
        #pragma unroll
        for (int d = 0; d < 4; ++d) o[d] = o[d] * alpha;
        // ---- write P (bf16) to wave-private sP[q][key] ----
        #pragma unroll
        for (int msub = 0; msub < 4; ++msub) {
            uint2 pw;
            pw.x = pk2(s[msub][0], s[msub][1]);
            pw.y = pk2(s[msub][2], s[msub][3]);
            *(uint2*)&sP[w][l16][msub * 16 + quad * 4] = pw;
        }
        // ---- O^T += Vt·P^T ----
        #pragma unroll
        for (int dsub = 0; dsub < 4; ++dsub) {
            #pragma unroll
            for (int kc2 = 0; kc2 < 2; ++kc2) {
                bf8 vf = *(const bf8*)&sV[kc2 * 4 + quad][dsub * 16 + l16][0];
                bf8 pf = *(const bf8*)&sP[w][l16][kc2 * 32 + quad * 8];
                o[dsub] = __builtin_amdgcn_mfma_f32_16x16x32_bf16(vf, pf, o[dsub], 0, 0, 0);
            }
        }
    }

    // ---- epilogue: O[tok][h*64 + d] = o/l ----
    const float inv = 1.f / lrun;
    #pragma unroll
    for (int dsub = 0; dsub < 4; ++dsub) {
        uint2 pw;
        pw.x = pk2(o[dsub][0] * inv, o[dsub][1] * inv);
        pw.y = pk2(o[dsub][2] * inv, o[dsub][3] * inv);
        *(uint2*)&O[qtok * 512 + h * 64 + dsub * 16 + quad * 4] = pw;
    }
}

// ===========================================================================
extern "C" void kernel_launch(void* const* d_in, const int* in_sizes, int n_in,
                              void* d_out, int out_size, void* d_ws, size_t ws_size,
                              hipStream_t stream) {
    const float* xq    = (const float*)d_in[0];
    const float* xk    = (const float*)d_in[1];
    const float* xv    = (const float*)d_in[2];
    const float* tq    = (const float*)d_in[3];
    const float* tk    = (const float*)d_in[4];
    const float* w_q   = (const float*)d_in[5];
    const float* w_k   = (const float*)d_in[6];
    const float* w_v   = (const float*)d_in[7];
    const float* w_out = (const float*)d_in[8];
    const float* b_out = (const float*)d_in[9];
    const float* kw1   = (const float*)d_in[10];
    const float* kb1   = (const float*)d_in[11];
    const float* kw2   = (const float*)d_in[12];

    // workspace: Q | K | Vt | Aq | Ak | Av | Wq | Wk | Wv | Wo   (50 MiB)
    u16* Q  = (u16*)d_ws;
    u16* Kp = Q  + NTOK;
    u16* Vt = Kp + NTOK;
    u16* Aq = Vt + NTOK;
    u16* Ak = Aq + NTOK;
    u16* Av = Ak + NTOK;
    u16* Wq = Av + NTOK;
    u16* Wk = Wq + 262144;
    u16* Wv = Wk + 262144;
    u16* Wo = Wv + 262144;
    u16* O  = Aq;            // Aq is dead after gemm1; reuse for attn output

    // --- one-time conversions (A's -> bf16, W's -> bf16 transposed) ---
    PArgs p;
    p.xs[0] = xq;  p.xs[1] = xk;  p.xs[2] = xv;
    p.ws[0] = w_q; p.ws[1] = w_k; p.ws[2] = w_v; p.ws[3] = w_out;
    p.dstA = Aq;   p.dstW = Wq;
    prep<<<dim3(1792), 256, 0, stream>>>(p);

    // --- QKV projections (V stored transposed per batch) ---
    GArgs gq;
    gq.A[0] = Aq;  gq.A[1] = Ak;  gq.A[2] = Av;
    gq.W[0] = Wq;  gq.W[1] = Wk;  gq.W[2] = Wv;
    gq.C[0] = Q;   gq.C[1] = Kp;  gq.C[2] = Vt;
    gq.bias = nullptr;
    gq.modeT[0] = 0; gq.modeT[1] = 0; gq.modeT[2] = 1;
    gq.outf32 = 0;
    gemm_mfma<<<dim3(4, 64, 3), 256, 0, stream>>>(gq);

    // --- fused attention ---
    attn_mfma<<<dim3(16, 8, Mb), 256, 0, stream>>>(Q, Kp, Vt, tq, tk,
                                                   kw1, kb1, kw2, O);

    // --- output projection (f32 + bias) ---
    GArgs go;
    go.A[0] = O;   go.A[1] = O;   go.A[2] = O;
    go.W[0] = Wo;  go.W[1] = Wo;  go.W[2] = Wo;
    go.C[0] = d_out; go.C[1] = d_out; go.C[2] = d_out;
    go.bias = b_out;
    go.modeT[0] = 0; go.modeT[1] = 0; go.modeT[2] = 0;
    go.outf32 = 1;
    gemm_mfma<<<dim3(4, 64, 1), 256, 0, stream>>>(go);
}